// Round 6
// baseline (323.796 us; speedup 1.0000x reference)
//
#include <hip/hip_runtime.h>
#include <hip/hip_fp16.h>
#include <hip/hip_bf16.h>

typedef short bf16x8 __attribute__((ext_vector_type(8)));
typedef _Float16 f16x8 __attribute__((ext_vector_type(8)));
typedef float f32x4 __attribute__((ext_vector_type(4)));

// ---------------------------------------------------------------------------
// K1: per-node log_map (bf16 out) + gate softmax; tail blocks transpose W.
// All fp32: coef(t) = acosh(1+t)/sqrt(t(2+t)) via series for small t.
// ---------------------------------------------------------------------------
__global__ __launch_bounds__(256) void k_tangent_gate(
    const float* __restrict__ x, const float* __restrict__ Wg,
    const float* __restrict__ bg, __hip_bfloat16* __restrict__ xtb,
    float* __restrict__ gate, const float* __restrict__ Wp,
    __hip_bfloat16* __restrict__ Wt, int N) {
  int tb = (N + 3) >> 2;
  if ((int)blockIdx.x >= tb) {
    int idx = (blockIdx.x - tb) * 256 + threadIdx.x;
    if (idx < 512 * 128) {
      int n = idx >> 7, k = idx & 127;
      Wt[idx] = __float2bfloat16(Wp[(size_t)k * 512 + n]);
    }
    return;
  }
  int wid = (blockIdx.x * blockDim.x + threadIdx.x) >> 6;
  int lane = threadIdx.x & 63;
  if (wid >= N) return;

  const float* xr = x + (size_t)wid * 128;
  float2 xv = *(const float2*)(xr + lane * 2);
  xv.x = fminf(fmaxf(xv.x, -10000.f), 10000.f);
  xv.y = fminf(fmaxf(xv.y, -10000.f), 10000.f);

  float p = xv.x * xv.x + xv.y * xv.y;
  if (lane == 0) p -= 2.f * xv.x * xv.x;
  #pragma unroll
  for (int s = 32; s; s >>= 1) p += __shfl_xor(p, s);
  float x0 = __shfl(xv.x, 0);

  // coef = acosh(cosd)/sqrt(cosd^2-1), cosd = x0/denom clipped at 1+1e-6
  float denom = sqrtf(fmaxf(fabsf(p), 1e-12f));
  float cosd = fmaxf(x0 / denom, 1.0f + 1e-6f);
  float t = cosd - 1.0f;
  float coef = (t < 1e-3f)
      ? 1.0f - t * (1.f / 3.f) + t * t * (2.f / 15.f)
      : acoshf(cosd) * rsqrtf(t * (2.f + t));

  float2 o;
  o.x = coef * ((lane == 0) ? 2.0f * xv.x : xv.x);
  o.y = coef * xv.y;
  __hip_bfloat162 hb = __float22bfloat162_rn(make_float2(o.x, o.y));
  *(__hip_bfloat162*)(xtb + (size_t)wid * 128 + lane * 2) = hb;

  const float4 w0 = *(const float4*)(Wg + (size_t)(lane * 2) * 4);
  const float4 w1 = *(const float4*)(Wg + (size_t)(lane * 2 + 1) * 4);
  float g0 = o.x * w0.x + o.y * w1.x;
  float g1 = o.x * w0.y + o.y * w1.y;
  float g2 = o.x * w0.z + o.y * w1.z;
  float g3 = o.x * w0.w + o.y * w1.w;
  #pragma unroll
  for (int s = 32; s; s >>= 1) {
    g0 += __shfl_xor(g0, s); g1 += __shfl_xor(g1, s);
    g2 += __shfl_xor(g2, s); g3 += __shfl_xor(g3, s);
  }
  g0 += bg[0]; g1 += bg[1]; g2 += bg[2]; g3 += bg[3];
  float m = fmaxf(fmaxf(g0, g1), fmaxf(g2, g3));
  float e0 = expf(g0 - m), e1 = expf(g1 - m), e2 = expf(g2 - m), e3 = expf(g3 - m);
  float z = e0 + e1 + e2 + e3;
  if (lane == 0)
    *(float4*)(gate + (size_t)wid * 4) = make_float4(e0 / z, e1 / z, e2 / z, e3 / z);
}

// ---------------------------------------------------------------------------
// K2: u_hat via bf16 MFMA; gate+bias fused epilogue; f16 output.
// ---------------------------------------------------------------------------
#define BM 64
__global__ __launch_bounds__(256) void k_uhat_mfma(
    const short* __restrict__ xtb, const float* __restrict__ gate,
    const short* __restrict__ Wt, const float* __restrict__ bp,
    __half* __restrict__ uh, int N) {
  __shared__ short sA[BM][136];
  __shared__ short sB[128][136];
  int tid = threadIdx.x;
  int lane = tid & 63;
  int w = tid >> 6;
  int m0 = blockIdx.x * BM;

  #pragma unroll
  for (int it = 0; it < 4; ++it) {
    int idx = it * 256 + tid;
    int r = idx >> 4, c = idx & 15;
    int4 v = make_int4(0, 0, 0, 0);
    if (m0 + r < N) v = *(const int4*)(xtb + (((size_t)(m0 + r)) << 7) + c * 8);
    *(int4*)(&sA[r][c * 8]) = v;
  }

  int mr = w * 16;
  int ri = lane & 15;
  int kg = lane >> 4;
  int rbase = m0 + mr + kg * 4;

  float fin[8][4];
  #pragma unroll
  for (int nt = 0; nt < 8; ++nt)
    #pragma unroll
    for (int q = 0; q < 4; ++q) fin[nt][q] = 0.f;

  for (int p = 0; p < 4; ++p) {
    __syncthreads();
    #pragma unroll
    for (int it = 0; it < 8; ++it) {
      int idx = it * 256 + tid;
      int r = idx >> 4, c = idx & 15;
      int4 v = *(const int4*)(Wt + (((size_t)p * 128 + r) << 7) + c * 8);
      *(int4*)(&sB[r][c * 8]) = v;
    }
    __syncthreads();

    bf16x8 af[4];
    #pragma unroll
    for (int ks = 0; ks < 4; ++ks)
      af[ks] = *(const bf16x8*)(&sA[mr + ri][ks * 32 + kg * 8]);

    #pragma unroll
    for (int nt = 0; nt < 8; ++nt) {
      f32x4 acc = {0.f, 0.f, 0.f, 0.f};
      #pragma unroll
      for (int ks = 0; ks < 4; ++ks) {
        bf16x8 bf = *(const bf16x8*)(&sB[nt * 16 + ri][ks * 32 + kg * 8]);
        acc = __builtin_amdgcn_mfma_f32_16x16x32_bf16(af[ks], bf, acc, 0, 0, 0);
      }
      float bpv = bp[p * 128 + nt * 16 + ri];
      #pragma unroll
      for (int q = 0; q < 4; ++q) {
        int rm = rbase + q;
        float g = (rm < N) ? gate[(size_t)rm * 4 + p] : 0.f;
        fin[nt][q] += g * (acc[q] + bpv);
      }
    }
  }
  #pragma unroll
  for (int nt = 0; nt < 8; ++nt) {
    int cn = nt * 16 + ri;
    #pragma unroll
    for (int q = 0; q < 4; ++q) {
      int rm = rbase + q;
      if (rm < N) uh[(size_t)rm * 128 + cn] = __float2half_rn(fin[nt][q]);
    }
  }
}

// ---------------------------------------------------------------------------
// CSR-by-col: histogram + hierarchical scan + scatter
// ---------------------------------------------------------------------------
__global__ void k_hist(const int* __restrict__ col, int* __restrict__ deg, int E) {
  int e = blockIdx.x * blockDim.x + threadIdx.x;
  if (e < E) atomicAdd(&deg[col[e]], 1);
}

#define SCH 1024
__global__ __launch_bounds__(256) void k_bsum(const int* __restrict__ deg,
                                              int* __restrict__ bsum, int N) {
  __shared__ int ws[4];
  int tid = threadIdx.x;
  int base = blockIdx.x * SCH;
  int v = 0;
  #pragma unroll
  for (int k = 0; k < 4; k++) {
    int i = base + k * 256 + tid;
    if (i < N) v += deg[i];
  }
  #pragma unroll
  for (int s = 32; s; s >>= 1) v += __shfl_xor(v, s);
  if ((tid & 63) == 0) ws[tid >> 6] = v;
  __syncthreads();
  if (tid == 0) bsum[blockIdx.x] = ws[0] + ws[1] + ws[2] + ws[3];
}

__global__ __launch_bounds__(64) void k_bscan(const int* __restrict__ bsum,
                                              int* __restrict__ boff,
                                              int* __restrict__ off, int NB, int N) {
  int lane = threadIdx.x;
  int carry = 0;
  for (int base = 0; base < NB; base += 64) {
    int i = base + lane;
    int v = (i < NB) ? bsum[i] : 0;
    int sc = v;
    #pragma unroll
    for (int s = 1; s < 64; s <<= 1) {
      int t = __shfl_up(sc, s);
      if (lane >= s) sc += t;
    }
    if (i < NB) boff[i] = carry + sc - v;
    carry += __shfl(sc, 63);
  }
  if (lane == 0) off[N] = carry;
}

__global__ __launch_bounds__(256) void k_scan2(const int* __restrict__ deg,
                                               const int* __restrict__ boff,
                                               int* __restrict__ off,
                                               int* __restrict__ cur, int N) {
  __shared__ int wtot[4];
  int tid = threadIdx.x;
  int lane = tid & 63;
  int base = blockIdx.x * SCH + tid * 4;
  int v[4];
  #pragma unroll
  for (int k = 0; k < 4; k++) v[k] = (base + k < N) ? deg[base + k] : 0;
  int tsum = v[0] + v[1] + v[2] + v[3];
  int sc = tsum;
  #pragma unroll
  for (int s = 1; s < 64; s <<= 1) {
    int t = __shfl_up(sc, s);
    if (lane >= s) sc += t;
  }
  if (lane == 63) wtot[tid >> 6] = sc;
  __syncthreads();
  int w = tid >> 6;
  int woff = 0;
  if (w > 0) woff += wtot[0];
  if (w > 1) woff += wtot[1];
  if (w > 2) woff += wtot[2];
  int pre = boff[blockIdx.x] + woff + sc - tsum;
  #pragma unroll
  for (int k = 0; k < 4; k++) {
    int i = base + k;
    if (i < N) { off[i] = pre; cur[i] = pre; }
    pre += v[k];
  }
}

__global__ void k_scatter(const int* __restrict__ row, const int* __restrict__ col,
                          int* __restrict__ cur, int* __restrict__ csr_row, int E) {
  int e = blockIdx.x * blockDim.x + threadIdx.x;
  if (e < E) {
    int p = atomicAdd(&cur[col[e]], 1);
    csr_row[p] = row[e];
  }
}

// ---------------------------------------------------------------------------
// K6: fused 3-iteration routing + squash + exp_map.
// 4 nodes / 256-thread block (1 wave each, no barriers, per-wave LDS slabs).
// u rows (f16) staged once in LDS; A-fragments (u) loaded once; per-round
// b-dots = 4(+4) MFMAs with B = s broadcast in all 16 cols; the MFMA C
// operand accumulates b across rounds (b never leaves registers).
// ---------------------------------------------------------------------------
#define CAP 24
#define SSTR 136   // su row stride in halves (17*8 -> 16B-aligned rows)
__global__ __launch_bounds__(256, 5) void k_route(
    const __half* __restrict__ uh, const float* __restrict__ bias,
    const int* __restrict__ csr_off, const int* __restrict__ csr_row,
    float* __restrict__ bg_ws, float* __restrict__ out, int N) {
  __shared__ ushort su[4][CAP][SSTR];
  __shared__ ushort ssb[4][128];
  __shared__ float se[4][32];
  int wv = threadIdx.x >> 6;
  int lane = threadIdx.x & 63;
  int j = blockIdx.x * 4 + wv;
  if (j >= N) return;
  int o0 = csr_off[j];
  int deg = csr_off[j + 1] - o0;
  int d0 = lane * 2;

  if (deg == 0) {
    *(float2*)(out + (size_t)j * 128 + d0) =
        make_float2((lane == 0) ? 1.f : 0.f, 0.f);
    return;
  }

  float2 bia = *(const float2*)(bias + d0);
  float s0 = 0.f, s1 = 0.f;

  if (deg <= CAP) {
    const uint* uhw = (const uint*)uh;   // half2-word view, 64 words/row
    int myrow = (lane < deg) ? csr_row[o0 + lane] : 0;

    // ---- parallel gathers into independent regs (wave-uniform guards) ----
    uint g[CAP];
    #pragma unroll
    for (int i = 0; i < CAP; ++i)
      if (i < deg) {
        int rr = __builtin_amdgcn_readlane(myrow, i);
        g[i] = uhw[(((size_t)(uint)rr) << 6) + lane];
      }
    // ---- round-0 sum (c = 1/deg) + LDS stage ----
    float a0 = 0.f, a1 = 0.f;
    #pragma unroll
    for (int i = 0; i < CAP; ++i)
      if (i < deg) {
        float2 uf = __half22float2(*(const __half2*)&g[i]);
        a0 += uf.x; a1 += uf.y;
        *(uint*)&su[wv][i][d0] = g[i];
      }

    // ---- A-fragments: u rows, loaded once (ds_read_b128) ----
    int ng = (deg + 15) >> 4;
    f16x8 af0[4], af1[4];
    {
      int er0 = lane & 15; if (er0 > CAP - 1) er0 = CAP - 1;
      #pragma unroll
      for (int kc = 0; kc < 4; ++kc)
        af0[kc] = *(const f16x8*)&su[wv][er0][kc * 32 + (lane >> 4) * 8];
      if (ng > 1) {
        int er1 = 16 + (lane & 15); if (er1 > CAP - 1) er1 = CAP - 1;
        #pragma unroll
        for (int kc = 0; kc < 4; ++kc)
          af1[kc] = *(const f16x8*)&su[wv][er1][kc * 32 + (lane >> 4) * 8];
      }
    }

    float invd = 1.f / (float)deg;
    s0 = a0 * invd + bia.x;
    s1 = a1 * invd + bia.y;
    {
      float ns = s0 * s0 + s1 * s1;
      #pragma unroll
      for (int s = 32; s; s >>= 1) ns += __shfl_xor(ns, s);
      float scale = (ns / (1.f + ns)) * rsqrtf(ns + 1e-9f);
      s0 *= scale; s1 *= scale;
    }

    f32x4 bacc0 = {0.f, 0.f, 0.f, 0.f};
    f32x4 bacc1 = {0.f, 0.f, 0.f, 0.f};
    #pragma unroll
    for (int r = 0; r < 2; ++r) {
      // publish s (f16) and build B-fragments (broadcast within kg group)
      *(__half2*)&ssb[wv][d0] = __floats2half2_rn(s0, s1);
      f16x8 bfr[4];
      #pragma unroll
      for (int kc = 0; kc < 4; ++kc)
        bfr[kc] = *(const f16x8*)&ssb[wv][kc * 32 + (lane >> 4) * 8];

      // b += dot(s, u_i): MFMA chain, C-operand accumulates across rounds
      #pragma unroll
      for (int kc = 0; kc < 4; ++kc)
        bacc0 = __builtin_amdgcn_mfma_f32_16x16x32_f16(af0[kc], bfr[kc], bacc0, 0, 0, 0);
      if (ng > 1) {
        #pragma unroll
        for (int kc = 0; kc < 4; ++kc)
          bacc1 = __builtin_amdgcn_mfma_f32_16x16x32_f16(af1[kc], bfr[kc], bacc1, 0, 0, 0);
      }

      // exp + z (every lane holds 4 edges' dots; cols identical)
      int eb0 = (lane >> 4) * 4;
      float ex0 = (eb0 + 0 < deg) ? __expf(bacc0[0]) : 0.f;
      float ex1 = (eb0 + 1 < deg) ? __expf(bacc0[1]) : 0.f;
      float ex2 = (eb0 + 2 < deg) ? __expf(bacc0[2]) : 0.f;
      float ex3 = (eb0 + 3 < deg) ? __expf(bacc0[3]) : 0.f;
      float z = ex0 + ex1 + ex2 + ex3;
      if ((lane & 15) == 0)
        *(float4*)&se[wv][eb0] = make_float4(ex0, ex1, ex2, ex3);
      if (ng > 1) {
        int eb1 = 16 + (lane >> 4) * 4;
        float y0 = (eb1 + 0 < deg) ? __expf(bacc1[0]) : 0.f;
        float y1 = (eb1 + 1 < deg) ? __expf(bacc1[1]) : 0.f;
        float y2 = (eb1 + 2 < deg) ? __expf(bacc1[2]) : 0.f;
        float y3 = (eb1 + 3 < deg) ? __expf(bacc1[3]) : 0.f;
        z += y0 + y1 + y2 + y3;
        if ((lane & 15) == 0)
          *(float4*)&se[wv][eb1] = make_float4(y0, y1, y2, y3);
      }
      z += __shfl_xor(z, 16);
      z += __shfl_xor(z, 32);

      // weighted sum (guard-unrolled: LDS reads batch)
      float invz = 1.f / z, w0 = 0.f, w1 = 0.f;
      #pragma unroll
      for (int i = 0; i < CAP; ++i)
        if (i < deg) {
          float ev = se[wv][i];
          float2 uf = __half22float2(*(const __half2*)&su[wv][i][d0]);
          w0 = fmaf(ev, uf.x, w0);
          w1 = fmaf(ev, uf.y, w1);
        }
      s0 = w0 * invz + bia.x;
      s1 = w1 * invz + bia.y;
      float ns = s0 * s0 + s1 * s1;
      #pragma unroll
      for (int s = 32; s; s >>= 1) ns += __shfl_xor(ns, s);
      float scale = (ns / (1.f + ns)) * rsqrtf(ns + 1e-9f);
      s0 *= scale; s1 *= scale;
    }
  } else {
    // fallback (deg > CAP, ~1 node expected): global-b, per-wave only
    float* b = bg_ws + o0;
    const __half2* uh2 = (const __half2*)uh;
    for (int i = lane; i < deg; i += 64) atomicExch(&b[i], 0.f);
    asm volatile("s_waitcnt vmcnt(0)" ::: "memory");

    for (int r = 0; r < 3; ++r) {
      float mx = -3.4e38f;
      for (int i = lane; i < deg; i += 64)
        mx = fmaxf(mx, atomicAdd(&b[i], 0.f));
      #pragma unroll
      for (int s = 32; s; s >>= 1) mx = fmaxf(mx, __shfl_xor(mx, s));
      float z = 0.f;
      for (int i = lane; i < deg; i += 64) z += expf(atomicAdd(&b[i], 0.f) - mx);
      #pragma unroll
      for (int s = 32; s; s >>= 1) z += __shfl_xor(z, s);
      float invz = 1.f / z;

      s0 = 0.f; s1 = 0.f;
      for (int i = 0; i < deg; ++i) {
        float c = expf(atomicAdd(&b[i], 0.f) - mx) * invz;
        int rr = csr_row[o0 + i];
        float2 uf = __half22float2(uh2[(((size_t)rr) << 6) + lane]);
        s0 = fmaf(c, uf.x, s0);
        s1 = fmaf(c, uf.y, s1);
      }
      s0 += bia.x; s1 += bia.y;

      float ns = s0 * s0 + s1 * s1;
      #pragma unroll
      for (int s = 32; s; s >>= 1) ns += __shfl_xor(ns, s);
      float scale = (ns / (1.f + ns)) * rsqrtf(ns + 1e-9f);
      s0 *= scale; s1 *= scale;

      if (r < 2) {
        for (int i = 0; i < deg; ++i) {
          int rr = csr_row[o0 + i];
          float2 uf = __half22float2(uh2[(((size_t)rr) << 6) + lane]);
          float pp = s0 * uf.x + s1 * uf.y;
          #pragma unroll
          for (int s = 32; s; s >>= 1) pp += __shfl_xor(pp, s);
          if (lane == 0) atomicAdd(&b[i], pp);
        }
        asm volatile("s_waitcnt vmcnt(0)" ::: "memory");
      }
    }
  }

  // exp_map(s, ref)
  float pn = s0 * s0 + s1 * s1;
  if (lane == 0) pn -= 2.f * s0 * s0;
  #pragma unroll
  for (int s = 32; s; s >>= 1) pn += __shfl_xor(pn, s);
  float vn = fminf(sqrtf(fabsf(pn) + 1e-12f), 10.f);
  float sh = sinhf(vn) / vn;
  float ov0 = sh * s0 + ((lane == 0) ? coshf(vn) : 0.f);
  float ov1 = sh * s1;
  *(float2*)(out + (size_t)j * 128 + d0) = make_float2(ov0, ov1);
}

// ---------------------------------------------------------------------------
extern "C" void kernel_launch(void* const* d_in, const int* in_sizes, int n_in,
                              void* d_out, int out_size, void* d_ws, size_t ws_size,
                              hipStream_t stream) {
  const float* x    = (const float*)d_in[0];
  const int*   ei   = (const int*)d_in[1];
  const float* Wp   = (const float*)d_in[2];
  const float* bp   = (const float*)d_in[3];
  const float* Wg   = (const float*)d_in[4];
  const float* bg   = (const float*)d_in[5];
  const float* bias = (const float*)d_in[6];
  float* out = (float*)d_out;

  int N = in_sizes[0] / 128;
  int E = in_sizes[1] / 2;
  const int* row = ei;
  const int* col = ei + E;
  int NB = (N + SCH - 1) / SCH;

  __hip_bfloat16* xtb = (__hip_bfloat16*)d_ws;                  // N*128 bf16
  __half* uhh = (__half*)(xtb + (size_t)N * 128);               // N*128 f16
  float* gate = (float*)(uhh + (size_t)N * 128);                // N*4 f32
  __hip_bfloat16* Wt = (__hip_bfloat16*)(gate + (size_t)N * 4); // 512*128 bf16
  float* bws = (float*)(Wt + 512 * 128);                        // E f32
  int* deg = (int*)(bws + E);
  int* off = deg + N;
  int* cur = off + N + 1;
  int* csr_row = cur + N;
  int* bsum = csr_row + E;
  int* boff = bsum + NB;

  int tb = (N + 3) / 4;
  hipMemsetAsync(deg, 0, (size_t)N * sizeof(int), stream);
  k_tangent_gate<<<tb + 256, 256, 0, stream>>>(x, Wg, bg, xtb, gate, Wp, Wt, N);
  k_uhat_mfma<<<(N + BM - 1) / BM, 256, 0, stream>>>(
      (const short*)xtb, gate, (const short*)Wt, bp, uhh, N);
  k_hist<<<(E + 255) / 256, 256, 0, stream>>>(col, deg, E);
  k_bsum<<<NB, 256, 0, stream>>>(deg, bsum, N);
  k_bscan<<<1, 64, 0, stream>>>(bsum, boff, off, NB, N);
  k_scan2<<<NB, 256, 0, stream>>>(deg, boff, off, cur, N);
  k_scatter<<<(E + 255) / 256, 256, 0, stream>>>(row, col, cur, csr_row, E);
  k_route<<<(N + 3) / 4, 256, 0, stream>>>(uhh, bias, off, csr_row, bws, out, N);
}

// Round 8
// 209.279 us; speedup vs baseline: 1.5472x; 1.5472x over previous
//
#include <hip/hip_runtime.h>
#include <hip/hip_fp16.h>
#include <hip/hip_bf16.h>

typedef short bf16x8 __attribute__((ext_vector_type(8)));
typedef float f32x4 __attribute__((ext_vector_type(4)));

#define LGKM_FENCE() asm volatile("s_waitcnt lgkmcnt(0)" ::: "memory")

// ---------------------------------------------------------------------------
// K1: per-node log_map (bf16 out) + gate softmax; tail blocks transpose W.
// All fp32: coef(t) = acosh(1+t)/sqrt(t(2+t)) via series for small t.
// ---------------------------------------------------------------------------
__global__ __launch_bounds__(256) void k_tangent_gate(
    const float* __restrict__ x, const float* __restrict__ Wg,
    const float* __restrict__ bg, __hip_bfloat16* __restrict__ xtb,
    float* __restrict__ gate, const float* __restrict__ Wp,
    __hip_bfloat16* __restrict__ Wt, int N) {
  int tb = (N + 3) >> 2;
  if ((int)blockIdx.x >= tb) {
    int idx = (blockIdx.x - tb) * 256 + threadIdx.x;
    if (idx < 512 * 128) {
      int n = idx >> 7, k = idx & 127;
      Wt[idx] = __float2bfloat16(Wp[(size_t)k * 512 + n]);
    }
    return;
  }
  int wid = (blockIdx.x * blockDim.x + threadIdx.x) >> 6;
  int lane = threadIdx.x & 63;
  if (wid >= N) return;

  const float* xr = x + (size_t)wid * 128;
  float2 xv = *(const float2*)(xr + lane * 2);
  xv.x = fminf(fmaxf(xv.x, -10000.f), 10000.f);
  xv.y = fminf(fmaxf(xv.y, -10000.f), 10000.f);

  float p = xv.x * xv.x + xv.y * xv.y;
  if (lane == 0) p -= 2.f * xv.x * xv.x;
  #pragma unroll
  for (int s = 32; s; s >>= 1) p += __shfl_xor(p, s);
  float x0 = __shfl(xv.x, 0);

  float denom = sqrtf(fmaxf(fabsf(p), 1e-12f));
  float cosd = fmaxf(x0 / denom, 1.0f + 1e-6f);
  float t = cosd - 1.0f;
  float coef = (t < 1e-3f)
      ? 1.0f - t * (1.f / 3.f) + t * t * (2.f / 15.f)
      : acoshf(cosd) * rsqrtf(t * (2.f + t));

  float2 o;
  o.x = coef * ((lane == 0) ? 2.0f * xv.x : xv.x);
  o.y = coef * xv.y;
  __hip_bfloat162 hb = __float22bfloat162_rn(make_float2(o.x, o.y));
  *(__hip_bfloat162*)(xtb + (size_t)wid * 128 + lane * 2) = hb;

  const float4 w0 = *(const float4*)(Wg + (size_t)(lane * 2) * 4);
  const float4 w1 = *(const float4*)(Wg + (size_t)(lane * 2 + 1) * 4);
  float g0 = o.x * w0.x + o.y * w1.x;
  float g1 = o.x * w0.y + o.y * w1.y;
  float g2 = o.x * w0.z + o.y * w1.z;
  float g3 = o.x * w0.w + o.y * w1.w;
  #pragma unroll
  for (int s = 32; s; s >>= 1) {
    g0 += __shfl_xor(g0, s); g1 += __shfl_xor(g1, s);
    g2 += __shfl_xor(g2, s); g3 += __shfl_xor(g3, s);
  }
  g0 += bg[0]; g1 += bg[1]; g2 += bg[2]; g3 += bg[3];
  float m = fmaxf(fmaxf(g0, g1), fmaxf(g2, g3));
  float e0 = expf(g0 - m), e1 = expf(g1 - m), e2 = expf(g2 - m), e3 = expf(g3 - m);
  float z = e0 + e1 + e2 + e3;
  if (lane == 0)
    *(float4*)(gate + (size_t)wid * 4) = make_float4(e0 / z, e1 / z, e2 / z, e3 / z);
}

// ---------------------------------------------------------------------------
// K2: u_hat via bf16 MFMA; gate+bias fused epilogue; f16 output.
// ---------------------------------------------------------------------------
#define BM 64
__global__ __launch_bounds__(256) void k_uhat_mfma(
    const short* __restrict__ xtb, const float* __restrict__ gate,
    const short* __restrict__ Wt, const float* __restrict__ bp,
    __half* __restrict__ uh, int N) {
  __shared__ short sA[BM][136];
  __shared__ short sB[128][136];
  int tid = threadIdx.x;
  int lane = tid & 63;
  int w = tid >> 6;
  int m0 = blockIdx.x * BM;

  #pragma unroll
  for (int it = 0; it < 4; ++it) {
    int idx = it * 256 + tid;
    int r = idx >> 4, c = idx & 15;
    int4 v = make_int4(0, 0, 0, 0);
    if (m0 + r < N) v = *(const int4*)(xtb + (((size_t)(m0 + r)) << 7) + c * 8);
    *(int4*)(&sA[r][c * 8]) = v;
  }

  int mr = w * 16;
  int ri = lane & 15;
  int kg = lane >> 4;
  int rbase = m0 + mr + kg * 4;

  float fin[8][4];
  #pragma unroll
  for (int nt = 0; nt < 8; ++nt)
    #pragma unroll
    for (int q = 0; q < 4; ++q) fin[nt][q] = 0.f;

  for (int p = 0; p < 4; ++p) {
    __syncthreads();
    #pragma unroll
    for (int it = 0; it < 8; ++it) {
      int idx = it * 256 + tid;
      int r = idx >> 4, c = idx & 15;
      int4 v = *(const int4*)(Wt + (((size_t)p * 128 + r) << 7) + c * 8);
      *(int4*)(&sB[r][c * 8]) = v;
    }
    __syncthreads();

    bf16x8 af[4];
    #pragma unroll
    for (int ks = 0; ks < 4; ++ks)
      af[ks] = *(const bf16x8*)(&sA[mr + ri][ks * 32 + kg * 8]);

    #pragma unroll
    for (int nt = 0; nt < 8; ++nt) {
      f32x4 acc = {0.f, 0.f, 0.f, 0.f};
      #pragma unroll
      for (int ks = 0; ks < 4; ++ks) {
        bf16x8 bf = *(const bf16x8*)(&sB[nt * 16 + ri][ks * 32 + kg * 8]);
        acc = __builtin_amdgcn_mfma_f32_16x16x32_bf16(af[ks], bf, acc, 0, 0, 0);
      }
      float bpv = bp[p * 128 + nt * 16 + ri];
      #pragma unroll
      for (int q = 0; q < 4; ++q) {
        int rm = rbase + q;
        float g = (rm < N) ? gate[(size_t)rm * 4 + p] : 0.f;
        fin[nt][q] += g * (acc[q] + bpv);
      }
    }
  }
  #pragma unroll
  for (int nt = 0; nt < 8; ++nt) {
    int cn = nt * 16 + ri;
    #pragma unroll
    for (int q = 0; q < 4; ++q) {
      int rm = rbase + q;
      if (rm < N) uh[(size_t)rm * 128 + cn] = __float2half_rn(fin[nt][q]);
    }
  }
}

// ---------------------------------------------------------------------------
// CSR-by-col: histogram + hierarchical scan + scatter
// ---------------------------------------------------------------------------
__global__ void k_hist(const int* __restrict__ col, int* __restrict__ deg, int E) {
  int e = blockIdx.x * blockDim.x + threadIdx.x;
  if (e < E) atomicAdd(&deg[col[e]], 1);
}

#define SCH 1024
__global__ __launch_bounds__(256) void k_bsum(const int* __restrict__ deg,
                                              int* __restrict__ bsum, int N) {
  __shared__ int ws[4];
  int tid = threadIdx.x;
  int base = blockIdx.x * SCH;
  int v = 0;
  #pragma unroll
  for (int k = 0; k < 4; k++) {
    int i = base + k * 256 + tid;
    if (i < N) v += deg[i];
  }
  #pragma unroll
  for (int s = 32; s; s >>= 1) v += __shfl_xor(v, s);
  if ((tid & 63) == 0) ws[tid >> 6] = v;
  __syncthreads();
  if (tid == 0) bsum[blockIdx.x] = ws[0] + ws[1] + ws[2] + ws[3];
}

__global__ __launch_bounds__(64) void k_bscan(const int* __restrict__ bsum,
                                              int* __restrict__ boff,
                                              int* __restrict__ off, int NB, int N) {
  int lane = threadIdx.x;
  int carry = 0;
  for (int base = 0; base < NB; base += 64) {
    int i = base + lane;
    int v = (i < NB) ? bsum[i] : 0;
    int sc = v;
    #pragma unroll
    for (int s = 1; s < 64; s <<= 1) {
      int t = __shfl_up(sc, s);
      if (lane >= s) sc += t;
    }
    if (i < NB) boff[i] = carry + sc - v;
    carry += __shfl(sc, 63);
  }
  if (lane == 0) off[N] = carry;
}

__global__ __launch_bounds__(256) void k_scan2(const int* __restrict__ deg,
                                               const int* __restrict__ boff,
                                               int* __restrict__ off,
                                               int* __restrict__ cur, int N) {
  __shared__ int wtot[4];
  int tid = threadIdx.x;
  int lane = tid & 63;
  int base = blockIdx.x * SCH + tid * 4;
  int v[4];
  #pragma unroll
  for (int k = 0; k < 4; k++) v[k] = (base + k < N) ? deg[base + k] : 0;
  int tsum = v[0] + v[1] + v[2] + v[3];
  int sc = tsum;
  #pragma unroll
  for (int s = 1; s < 64; s <<= 1) {
    int t = __shfl_up(sc, s);
    if (lane >= s) sc += t;
  }
  if (lane == 63) wtot[tid >> 6] = sc;
  __syncthreads();
  int w = tid >> 6;
  int woff = 0;
  if (w > 0) woff += wtot[0];
  if (w > 1) woff += wtot[1];
  if (w > 2) woff += wtot[2];
  int pre = boff[blockIdx.x] + woff + sc - tsum;
  #pragma unroll
  for (int k = 0; k < 4; k++) {
    int i = base + k;
    if (i < N) { off[i] = pre; cur[i] = pre; }
    pre += v[k];
  }
}

__global__ void k_scatter(const int* __restrict__ row, const int* __restrict__ col,
                          int* __restrict__ cur, int* __restrict__ csr_row, int E) {
  int e = blockIdx.x * blockDim.x + threadIdx.x;
  if (e < E) {
    int p = atomicAdd(&cur[col[e]], 1);
    csr_row[p] = row[e];
  }
}

// ---------------------------------------------------------------------------
// K6: fused 3-iteration routing + squash + exp_map.
// One wave per node (64-thread blocks, ~8.8 KB LDS -> 16 blocks/CU).
// Staging: fully parallel register gathers (unrolled, wave-uniform guards).
// b-dots: lane-pair (edge e=lane>>1, half h=lane&1) scans LDS u row vs
// published s -> ONE shfl_xor per round; b accumulates in registers.
// Weighted sum: broadcast se[] reads, redundant z per lane, no reductions.
// LDS stride 66 words => <=2 lanes/bank everywhere (free).
// ---------------------------------------------------------------------------
#define CAP 32
#define STR 66
__global__ __launch_bounds__(64, 4) void k_route(
    const __half* __restrict__ uh, const float* __restrict__ bias,
    const int* __restrict__ csr_off, const int* __restrict__ csr_row,
    float* __restrict__ bg_ws, float* __restrict__ out, int N) {
  __shared__ uint su[CAP * STR];   // u rows as half2 words
  __shared__ uint ssw[64];         // s as half2
  __shared__ float se[CAP];        // exp(b)
  int lane = threadIdx.x;
  int j = blockIdx.x;
  int o0 = csr_off[j];
  int deg = csr_off[j + 1] - o0;
  int d0 = lane * 2;

  if (deg == 0) {
    *(float2*)(out + (size_t)j * 128 + d0) =
        make_float2((lane == 0) ? 1.f : 0.f, 0.f);
    return;
  }

  float2 bia = *(const float2*)(bias + d0);
  float s0 = 0.f, s1 = 0.f;

  if (deg <= CAP) {
    const uint* uhw = (const uint*)uh;   // half2-word view, 64 words/row
    int myrow = (lane < deg) ? csr_row[o0 + lane] : 0;

    // ---- parallel gathers: independent dest regs, one round-trip ----
    uint g[CAP];
    #pragma unroll
    for (int i = 0; i < CAP; ++i)
      if (i < deg) {
        int rr = __builtin_amdgcn_readlane(myrow, i);
        g[i] = uhw[(((size_t)(uint)rr) << 6) + lane];
      }

    // ---- stage to LDS + round-0 sum (c = 1/deg exactly) ----
    float a0 = 0.f, a1 = 0.f;
    #pragma unroll
    for (int i = 0; i < CAP; ++i)
      if (i < deg) {
        su[i * STR + lane] = g[i];
        float2 uf = __half22float2(*(const __half2*)&g[i]);
        a0 += uf.x; a1 += uf.y;
      }

    float invd = 1.f / (float)deg;
    s0 = a0 * invd + bia.x;
    s1 = a1 * invd + bia.y;
    {
      float ns = s0 * s0 + s1 * s1;
      #pragma unroll
      for (int s = 32; s; s >>= 1) ns += __shfl_xor(ns, s);
      float scale = (ns / (1.f + ns)) * rsqrtf(ns + 1e-9f);
      s0 *= scale; s1 *= scale;
    }

    int e = lane >> 1, h = lane & 1;
    const uint* surow = &su[e * STR + h * 32];
    const uint* ssrow = &ssw[h * 32];
    bool act = (e < deg);
    float b = 0.f;

    #pragma unroll
    for (int r = 0; r < 2; ++r) {
      // publish s (f16) — bit-cast half2 -> uint via pointer
      __half2 sh2 = __floats2half2_rn(s0, s1);
      ssw[lane] = *(const uint*)&sh2;
      LGKM_FENCE();

      // per-edge dot: lane-pair scans 32+32 half2 words
      float acc = 0.f;
      #pragma unroll
      for (int w2 = 0; w2 < 16; ++w2) {
        uint2 uw = *(const uint2*)&surow[w2 * 2];
        uint2 sw = *(const uint2*)&ssrow[w2 * 2];
        float2 u0 = __half22float2(*(const __half2*)&uw.x);
        float2 u1 = __half22float2(*(const __half2*)&uw.y);
        float2 v0 = __half22float2(*(const __half2*)&sw.x);
        float2 v1 = __half22float2(*(const __half2*)&sw.y);
        acc = fmaf(u0.x, v0.x, acc);
        acc = fmaf(u0.y, v0.y, acc);
        acc = fmaf(u1.x, v1.x, acc);
        acc = fmaf(u1.y, v1.y, acc);
      }
      acc += __shfl_xor(acc, 1);
      b += acc;
      if (act && h == 0) se[e] = __expf(b);
      LGKM_FENCE();

      // weighted sum: broadcast se reads, redundant z, no reductions
      float z = 0.f, w0 = 0.f, w1 = 0.f;
      #pragma unroll
      for (int i = 0; i < CAP; ++i)
        if (i < deg) {
          float ev = se[i];
          float2 uf = __half22float2(*(const __half2*)&su[i * STR + lane]);
          z += ev;
          w0 = fmaf(ev, uf.x, w0);
          w1 = fmaf(ev, uf.y, w1);
        }
      float invz = 1.f / z;
      s0 = w0 * invz + bia.x;
      s1 = w1 * invz + bia.y;
      float ns = s0 * s0 + s1 * s1;
      #pragma unroll
      for (int s = 32; s; s >>= 1) ns += __shfl_xor(ns, s);
      float scale = (ns / (1.f + ns)) * rsqrtf(ns + 1e-9f);
      s0 *= scale; s1 *= scale;
    }
  } else {
    // fallback (deg > CAP, ~never for Poisson(10)): global-b, per-wave only
    float* b = bg_ws + o0;
    const __half2* uh2 = (const __half2*)uh;
    for (int i = lane; i < deg; i += 64) atomicExch(&b[i], 0.f);
    asm volatile("s_waitcnt vmcnt(0)" ::: "memory");

    for (int r = 0; r < 3; ++r) {
      float mx = -3.4e38f;
      for (int i = lane; i < deg; i += 64)
        mx = fmaxf(mx, atomicAdd(&b[i], 0.f));
      #pragma unroll
      for (int s = 32; s; s >>= 1) mx = fmaxf(mx, __shfl_xor(mx, s));
      float z = 0.f;
      for (int i = lane; i < deg; i += 64) z += expf(atomicAdd(&b[i], 0.f) - mx);
      #pragma unroll
      for (int s = 32; s; s >>= 1) z += __shfl_xor(z, s);
      float invz = 1.f / z;

      s0 = 0.f; s1 = 0.f;
      for (int i = 0; i < deg; ++i) {
        float c = expf(atomicAdd(&b[i], 0.f) - mx) * invz;
        int rr = csr_row[o0 + i];
        float2 uf = __half22float2(uh2[(((size_t)rr) << 6) + lane]);
        s0 = fmaf(c, uf.x, s0);
        s1 = fmaf(c, uf.y, s1);
      }
      s0 += bia.x; s1 += bia.y;

      float ns = s0 * s0 + s1 * s1;
      #pragma unroll
      for (int s = 32; s; s >>= 1) ns += __shfl_xor(ns, s);
      float scale = (ns / (1.f + ns)) * rsqrtf(ns + 1e-9f);
      s0 *= scale; s1 *= scale;

      if (r < 2) {
        for (int i = 0; i < deg; ++i) {
          int rr = csr_row[o0 + i];
          float2 uf = __half22float2(uh2[(((size_t)rr) << 6) + lane]);
          float pp = s0 * uf.x + s1 * uf.y;
          #pragma unroll
          for (int s = 32; s; s >>= 1) pp += __shfl_xor(pp, s);
          if (lane == 0) atomicAdd(&b[i], pp);
        }
        asm volatile("s_waitcnt vmcnt(0)" ::: "memory");
      }
    }
  }

  // exp_map(s, ref)
  float pn = s0 * s0 + s1 * s1;
  if (lane == 0) pn -= 2.f * s0 * s0;
  #pragma unroll
  for (int s = 32; s; s >>= 1) pn += __shfl_xor(pn, s);
  float vn = fminf(sqrtf(fabsf(pn) + 1e-12f), 10.f);
  float sh = sinhf(vn) / vn;
  float ov0 = sh * s0 + ((lane == 0) ? coshf(vn) : 0.f);
  float ov1 = sh * s1;
  *(float2*)(out + (size_t)j * 128 + d0) = make_float2(ov0, ov1);
}

// ---------------------------------------------------------------------------
extern "C" void kernel_launch(void* const* d_in, const int* in_sizes, int n_in,
                              void* d_out, int out_size, void* d_ws, size_t ws_size,
                              hipStream_t stream) {
  const float* x    = (const float*)d_in[0];
  const int*   ei   = (const int*)d_in[1];
  const float* Wp   = (const float*)d_in[2];
  const float* bp   = (const float*)d_in[3];
  const float* Wg   = (const float*)d_in[4];
  const float* bg   = (const float*)d_in[5];
  const float* bias = (const float*)d_in[6];
  float* out = (float*)d_out;

  int N = in_sizes[0] / 128;
  int E = in_sizes[1] / 2;
  const int* row = ei;
  const int* col = ei + E;
  int NB = (N + SCH - 1) / SCH;

  __hip_bfloat16* xtb = (__hip_bfloat16*)d_ws;                  // N*128 bf16
  __half* uhh = (__half*)(xtb + (size_t)N * 128);               // N*128 f16
  float* gate = (float*)(uhh + (size_t)N * 128);                // N*4 f32
  __hip_bfloat16* Wt = (__hip_bfloat16*)(gate + (size_t)N * 4); // 512*128 bf16
  float* bws = (float*)(Wt + 512 * 128);                        // E f32
  int* deg = (int*)(bws + E);
  int* off = deg + N;
  int* cur = off + N + 1;
  int* csr_row = cur + N;
  int* bsum = csr_row + E;
  int* boff = bsum + NB;

  int tb = (N + 3) / 4;
  (void)hipMemsetAsync(deg, 0, (size_t)N * sizeof(int), stream);
  k_tangent_gate<<<tb + 256, 256, 0, stream>>>(x, Wg, bg, xtb, gate, Wp, Wt, N);
  k_uhat_mfma<<<(N + BM - 1) / BM, 256, 0, stream>>>(
      (const short*)xtb, gate, (const short*)Wt, bp, uhh, N);
  k_hist<<<(E + 255) / 256, 256, 0, stream>>>(col, deg, E);
  k_bsum<<<NB, 256, 0, stream>>>(deg, bsum, N);
  k_bscan<<<1, 64, 0, stream>>>(bsum, boff, off, NB, N);
  k_scan2<<<NB, 256, 0, stream>>>(deg, boff, off, cur, N);
  k_scatter<<<(E + 255) / 256, 256, 0, stream>>>(row, col, cur, csr_row, E);
  k_route<<<N, 64, 0, stream>>>(uhh, bias, off, csr_row, bws, out, N);
}